// Round 8
// baseline (439.321 us; speedup 1.0000x reference)
//
#include <hip/hip_runtime.h>
#include <hip/hip_bf16.h>
#include <stdint.h>

// Problem dims
#define DMODEL 1024
#define DHID   1024
#define NBATCH 8
#define LSEQ   2048
#define MROWS  (NBATCH * LSEQ)   // 16384
#define KCAT   2048              // [h | x] concat K
#define CH     32                // scan chunk length
#define NCH    64                // LSEQ / CH
#define BH     (NBATCH * DHID)   // 8192
#define CPT    4                 // channels per scan thread

typedef __attribute__((ext_vector_type(8))) short  short8;
typedef __attribute__((ext_vector_type(4))) short  s16x4;
typedef __attribute__((ext_vector_type(8))) __bf16 bf16x8;
typedef __attribute__((ext_vector_type(4))) float  f32x4;

__device__ __forceinline__ unsigned short f2bf(float f) {
  union { float f; unsigned int u; } v; v.f = f;
  unsigned int u = v.u;
  u += 0x7fffu + ((u >> 16) & 1u);   // round-to-nearest-even
  return (unsigned short)(u >> 16);
}

__device__ __forceinline__ float bf2f(unsigned short s) {
  union { unsigned int u; float f; } v; v.u = ((unsigned int)s) << 16;
  return v.f;
}

// Fast softplus: hardware v_exp_f32/v_log_f32 (~10 VALU ops) instead of libm
// expf+log1pf (branchy ~50-70 ops; was VALUBusy 81% / +79us in round 5;
// round 7 confirmed 36% / 98us). Max abs err ~6e-8, below bf16 rounding.
__device__ __forceinline__ float softplus_f(float x) {
  return fmaxf(x, 0.f) + __logf(1.f + __expf(-fabsf(x)));
}

__device__ __forceinline__ short8 pack8(float4 a, float4 b) {
  short8 o;
  o[0] = (short)f2bf(a.x); o[1] = (short)f2bf(a.y);
  o[2] = (short)f2bf(a.z); o[3] = (short)f2bf(a.w);
  o[4] = (short)f2bf(b.x); o[5] = (short)f2bf(b.y);
  o[6] = (short)f2bf(b.z); o[7] = (short)f2bf(b.w);
  return o;
}

// ---- one cast kernel: x -> A2[:,1024:], W1 (interleaved dw/Bw), W2 -------
// W1 row 2h = dw[h,:], row 2h+1 = Bw[h,:]  -> G1 columns become (d,bb) pairs
__global__ __launch_bounds__(256)
void cast_all_kernel(const float* __restrict__ x,
                     const float* __restrict__ dw, const float* __restrict__ Bw,
                     const float* __restrict__ Cw, const float* __restrict__ Dw,
                     unsigned short* __restrict__ A2,
                     unsigned short* __restrict__ W1, unsigned short* __restrict__ W2) {
  const size_t MX = (size_t)MROWS * 1024;       // 16M: x
  const size_t M1 = (size_t)1024 * 1024;        // 1M
  size_t i8 = ((size_t)blockIdx.x * 256 + threadIdx.x) * 8;
  if (i8 < MX) {
    size_t row = i8 >> 10; int col = (int)(i8 & 1023);
    const float4* p = (const float4*)(x + i8);
    *(short8*)(A2 + row * (size_t)KCAT + 1024 + col) = pack8(p[0], p[1]);
  } else if (i8 < MX + 2 * M1) {                // W1 interleaved: row r, h=r>>1
    size_t k = i8 - MX;
    size_t h = k >> 11;                          // channel
    int c = (int)(k & 1023);                     // column
    const float* src = ((k >> 10) & 1) ? (Bw + h * 1024 + c) : (dw + h * 1024 + c);
    const float4* p = (const float4*)src;
    *(short8*)(W1 + k) = pack8(p[0], p[1]);
  } else {                                      // W2 row d: [Cw[d,:] | Dw[d,:]]
    size_t k = i8 - MX - 2 * M1;
    size_t d = k >> 11; int c = (int)(k & 2047);
    const float* src = (c < 1024) ? (Cw + d * 1024 + c) : (Dw + d * 1024 + (c - 1024));
    const float4* p = (const float4*)src;
    *(short8*)(W2 + k) = pack8(p[0], p[1]);
  }
}

// ---- GEMM: C[M,N] = A[M,K] @ B[N,K]^T ------------------------------------
// Round-0 proven structure (128^2 tile, 4 waves, 2 syncthreads/K-step) with
// ONE isolated change: fragment-major LDS staging (round-4's verified
// pattern) to kill the 8.39M SQ_LDS_BANK_CONFLICT measured in rounds 0/5/7.
// Fragment f = rows [f*16,f*16+16) x 32 cols; element (row=f*16+l16,
// col=quad*8+j) at short-offset f*512 + lane*8 + j. Every ds_read_b128 is
// base + lane*16B (conflict-free; measured 0 in r2/r3/r4); global_load_lds
// linear dest matches via the pre-permuted global source (m173 pattern) --
// the per-instruction global footprint (16 rows x 64B) is identical to the
// old stage, so HBM/L2 coalescing is unchanged.
// mode 0: f32 out, += bias0[n]+bias1[n]
// mode 2: SSM pointwise epilogue (GEMM1): n even -> d=softplus(acc+db[h]),
//         n odd -> bb = d_neighbor * (acc + Bb[h]); bf16 out. h = n>>1.
__device__ __forceinline__ void stage_frag(const unsigned short* __restrict__ g0,
                                           int ld, unsigned short* s0,
                                           int wave, int quad, int l16) {
#pragma unroll
  for (int s = 0; s < 2; ++s) {
    int f = s * 4 + wave;                                   // wave-uniform frag id
    const unsigned short* g = g0 + (size_t)(f * 16 + l16) * ld + quad * 8;
    unsigned short* sd = s0 + (size_t)f * 512;              // uniform base (+lane*16B)
    __builtin_amdgcn_global_load_lds(
        (const __attribute__((address_space(1))) unsigned int*)g,
        (__attribute__((address_space(3))) unsigned int*)sd, 16, 0, 0);
  }
}

__global__ __launch_bounds__(256, 4)
void gemm_bt(const unsigned short* __restrict__ A, int lda,
             const unsigned short* __restrict__ B, int ldb,
             void* __restrict__ Cp, int ldc, int K, int mode,
             const float* __restrict__ bias0, const float* __restrict__ bias1) {
  __shared__ __align__(16) unsigned short As[128 * 32];
  __shared__ __align__(16) unsigned short Bs[128 * 32];
  const int t = threadIdx.x;
  const int lane = t & 63, wave = t >> 6;
  const int quad = lane >> 4, l16 = lane & 15;

  // XCD-aware swizzle: each XCD (bid%8) owns a contiguous M-band, N-fastest,
  // so the weight matrix stays resident in that XCD's 4 MB L2.
  const int Nt = gridDim.x, Mt = gridDim.y;
  int bid = blockIdx.y * Nt + blockIdx.x;
  int xcd = bid & 7;
  int slot = bid >> 3;
  int lm = slot / Nt;
  int ln = slot - lm * Nt;
  const int m0 = (xcd * (Mt >> 3) + lm) * 128;
  const int n0 = ln * 128;

  const int wm = (wave & 1) * 64, wn = (wave >> 1) * 64;
  const int fa = (wave & 1) * 4, fb = (wave >> 1) * 4;   // fragment bases

  const unsigned short* Ab = A + (size_t)m0 * lda;
  const unsigned short* Bb = B + (size_t)n0 * ldb;

  f32x4 acc[4][4] = {};

  for (int k0 = 0; k0 < K; k0 += 32) {
    stage_frag(Ab + k0, lda, As, wave, quad, l16);
    stage_frag(Bb + k0, ldb, Bs, wave, quad, l16);
    __syncthreads();
    short8 af[4], bfr[4];
#pragma unroll
    for (int i = 0; i < 4; ++i)
      af[i] = *(const short8*)(As + (size_t)(fa + i) * 512 + lane * 8);
#pragma unroll
    for (int j = 0; j < 4; ++j)
      bfr[j] = *(const short8*)(Bs + (size_t)(fb + j) * 512 + lane * 8);
#pragma unroll
    for (int i = 0; i < 4; ++i)
#pragma unroll
      for (int j = 0; j < 4; ++j)
        acc[i][j] = __builtin_amdgcn_mfma_f32_16x16x32_bf16(
            __builtin_bit_cast(bf16x8, af[i]),
            __builtin_bit_cast(bf16x8, bfr[j]), acc[i][j], 0, 0, 0);
    __syncthreads();
  }

  if (mode == 0) {
    float* C = (float*)Cp;
#pragma unroll
    for (int i = 0; i < 4; ++i)
#pragma unroll
      for (int j = 0; j < 4; ++j) {
        int n = n0 + wn + j * 16 + l16;
        int mb = m0 + wm + i * 16 + quad * 4;
        float badd = bias0[n] + bias1[n];
#pragma unroll
        for (int r = 0; r < 4; ++r)
          C[(size_t)(mb + r) * ldc + n] = acc[i][j][r] + badd;
      }
  } else {
    // mode 2: fused SSM pointwise. Adjacent lanes hold (dpre, bpre) of the
    // same channel h (W1 rows interleaved); one shfl_xor(1) moves d across.
    unsigned short* C16 = (unsigned short*)Cp;
#pragma unroll
    for (int i = 0; i < 4; ++i)
#pragma unroll
      for (int j = 0; j < 4; ++j) {
        int n = n0 + wn + j * 16 + l16;
        int mb = m0 + wm + i * 16 + quad * 4;
        int h = n >> 1;
        bool isd = (n & 1) == 0;
        float bias = isd ? bias0[h] : bias1[h];   // db[h] : Bb[h]
#pragma unroll
        for (int r = 0; r < 4; ++r) {
          float v = acc[i][j][r] + bias;          // dpre+db  or  bpre+Bb
          float d = softplus_f(v);                // valid on even lanes
          float dn = __shfl_xor(d, 1);            // neighbor's d (for odd lanes)
          float ov = isd ? d : dn * v;            // d  or  bb = d*(bpre+Bb)
          C16[(size_t)(mb + r) * ldc + n] = f2bf(ov);
        }
      }
  }
}

// ---- scan pass A: per-chunk carries (G1 read-only) ----------------------
// G1 row layout: [d0,bb0,d1,bb1,...] interleaved pairs (2048 wide).
// Ring-of-3 prefetch: 2 outstanding 16B loads/thread (stride 4KB) to cover
// HBM latency at only 8 waves/CU.
__global__ __launch_bounds__(256)
void scan_carry_kernel(const unsigned short* __restrict__ G1,
                       const float* __restrict__ Av, float2* __restrict__ carr) {
  int t = blockIdx.x * 256 + threadIdx.x;      // 131072 = 8 * 64 * 256
  int ho = t & 255, chunk = (t >> 8) & (NCH - 1), b = t >> 14;
  int h0 = ho << 2;
  float4 A0 = *(const float4*)(Av + h0);
  float Ah[4] = {A0.x, A0.y, A0.z, A0.w};
  const unsigned short* base = G1 + ((size_t)(b * LSEQ + chunk * CH)) * KCAT + 2 * h0;
  float hs[4] = {}, sd[4] = {};
  short8 v0 = *(const short8*)(base);
  short8 v1 = *(const short8*)(base + KCAT);
#pragma unroll 4
  for (int l = 0; l < CH; ++l) {
    short8 v2 = v1;
    if (l + 2 < CH)
      v2 = *(const short8*)(base + (size_t)(l + 2) * KCAT);
#pragma unroll
    for (int j = 0; j < 4; ++j) {
      float d  = bf2f((unsigned short)v0[2 * j]);
      float bb = bf2f((unsigned short)v0[2 * j + 1]);
      sd[j] += d;
      hs[j] = fmaf(__expf(d * Ah[j]), hs[j], bb);
    }
    v0 = v1; v1 = v2;
  }
  float2* cb = carr + (size_t)chunk * BH + b * 1024 + h0;
#pragma unroll
  for (int j = 0; j < 4; ++j)
    cb[j] = make_float2(__expf(Ah[j] * sd[j]), hs[j]);
}

// ---- scan pass B: compose carries (lane-contiguous) ---------------------
__global__ __launch_bounds__(256)
void scan_comb_kernel(const float2* __restrict__ carr, float* __restrict__ Hc) {
  int t = blockIdx.x * 256 + threadIdx.x;   // 8192 = B*DH
  float H = 0.f;
#pragma unroll
  for (int c = 0; c < NCH; ++c) {
    float2 ah = carr[(size_t)c * BH + t];
    Hc[(size_t)c * BH + t] = H;              // carry-in for chunk c
    H = fmaf(ah.x, H, ah.y);
  }
}

// ---- scan pass C: recompute with carry, emit h bf16 into A2[:,0:1024] ---
__global__ __launch_bounds__(256)
void scan_final_kernel(const unsigned short* __restrict__ G1,
                       const float* __restrict__ Av, const float* __restrict__ Hc,
                       unsigned short* __restrict__ A2) {
  int t = blockIdx.x * 256 + threadIdx.x;      // 131072
  int ho = t & 255, chunk = (t >> 8) & (NCH - 1), b = t >> 14;
  int h0 = ho << 2;
  float4 A0 = *(const float4*)(Av + h0);
  float Ah[4] = {A0.x, A0.y, A0.z, A0.w};
  const unsigned short* base = G1 + ((size_t)(b * LSEQ + chunk * CH)) * KCAT + 2 * h0;
  unsigned short* obase = A2 + ((size_t)(b * LSEQ + chunk * CH)) * KCAT + h0;
  const float* hb = Hc + (size_t)chunk * BH + b * 1024 + h0;
  float hs[4];
#pragma unroll
  for (int j = 0; j < 4; ++j) hs[j] = hb[j];
  short8 v0 = *(const short8*)(base);
  short8 v1 = *(const short8*)(base + KCAT);
#pragma unroll 4
  for (int l = 0; l < CH; ++l) {
    short8 v2 = v1;
    if (l + 2 < CH)
      v2 = *(const short8*)(base + (size_t)(l + 2) * KCAT);
    s16x4 o;
#pragma unroll
    for (int j = 0; j < 4; ++j) {
      float d  = bf2f((unsigned short)v0[2 * j]);
      float bb = bf2f((unsigned short)v0[2 * j + 1]);
      hs[j] = fmaf(__expf(d * Ah[j]), hs[j], bb);
      o[j] = (short)f2bf(hs[j]);
    }
    *(s16x4*)(obase + (size_t)l * KCAT) = o;
    v0 = v1; v1 = v2;
  }
}

extern "C" void kernel_launch(void* const* d_in, const int* in_sizes, int n_in,
                              void* d_out, int out_size, void* d_ws, size_t ws_size,
                              hipStream_t stream) {
  const float* x  = (const float*)d_in[0];
  const float* Av = (const float*)d_in[1];
  const float* Bw = (const float*)d_in[2];
  const float* Bb = (const float*)d_in[3];
  const float* Cw = (const float*)d_in[4];
  const float* Cb = (const float*)d_in[5];
  const float* Dw = (const float*)d_in[6];
  const float* Db = (const float*)d_in[7];
  const float* dw = (const float*)d_in[8];
  const float* db = (const float*)d_in[9];
  float* out = (float*)d_out;

  // Workspace (138 MiB):
  //   A2 [16384,2048] bf16 = 64 MiB ([h | x])
  //   G1 [16384,2048] bf16 = 64 MiB ((d,bb) interleaved pairs)
  //   W1 [2048,1024]  bf16 =  4 MiB (interleaved dw/Bw; reused as carr)
  //   W2 [1024,2048]  bf16 =  4 MiB ([Cw|Dw])
  //   Hc [64,8192]    f32  =  2 MiB
  const size_t sz_big = (size_t)MROWS * KCAT * 2;
  const size_t sz_w   = (size_t)2048 * 1024 * 2;
  const size_t sz_hc  = (size_t)NCH * BH * 4;
  const size_t need = 2 * sz_big + 2 * sz_w + sz_hc;
  if (ws_size < need) return;

  char* w = (char*)d_ws;
  unsigned short* A2 = (unsigned short*)w; w += sz_big;
  unsigned short* G1 = (unsigned short*)w; w += sz_big;
  unsigned short* W1 = (unsigned short*)w; w += sz_w;
  unsigned short* W2 = (unsigned short*)w; w += sz_w;
  float* Hc = (float*)w;                   w += sz_hc;
  float2* carr = (float2*)W1;  // W1 dead after GEMM1; carr = NCH*BH*8 = 4 MiB exactly

  // cast everything (x, W1, W2) in one launch
  const size_t cast_elems = (size_t)MROWS * 1024 + 2 * (size_t)2048 * 1024;
  cast_all_kernel<<<(int)(cast_elems / (256 * 8)), 256, 0, stream>>>(
      x, dw, Bw, Cw, Dw, A2, W1, W2);

  // GEMM1 + fused pointwise: G1 = pointwise(x @ W1^T)  (M=16384,N=2048,K=1024)
  dim3 g1(KCAT / 128, MROWS / 128);        // (16, 128)
  gemm_bt<<<g1, 256, 0, stream>>>(A2 + 1024, KCAT, W1, 1024, G1, KCAT, 1024, 2,
                                  db, Bb);

  // chunked scan: carries (read-only over G1), compose, final
  scan_carry_kernel<<<(NBATCH * NCH * (DHID / CPT)) / 256, 256, 0, stream>>>(
      G1, Av, carr);
  scan_comb_kernel<<<BH / 256, 256, 0, stream>>>(carr, Hc);
  scan_final_kernel<<<(NBATCH * NCH * (DHID / CPT)) / 256, 256, 0, stream>>>(
      G1, Av, Hc, A2);

  // GEMM2: out = [h | x] @ [Cw|Dw]^T + Cb + Db  (M=16384,N=1024,K=2048), f32
  dim3 g2(DMODEL / 128, MROWS / 128);      // (8, 128)
  gemm_bt<<<g2, 256, 0, stream>>>(A2, KCAT, W2, KCAT, out, DMODEL, KCAT, 0, Cb, Db);
}

// Round 9
// 341.291 us; speedup vs baseline: 1.2872x; 1.2872x over previous
//
#include <hip/hip_runtime.h>
#include <hip/hip_bf16.h>
#include <stdint.h>

// Problem dims
#define DMODEL 1024
#define DHID   1024
#define NBATCH 8
#define LSEQ   2048
#define MROWS  (NBATCH * LSEQ)   // 16384
#define KCAT   2048              // [h | x] concat K
#define CH     32                // scan chunk length
#define NCH    64                // LSEQ / CH
#define BH     (NBATCH * DHID)   // 8192
#define CPT    4                 // channels per scan thread

typedef __attribute__((ext_vector_type(8))) short  short8;
typedef __attribute__((ext_vector_type(4))) short  s16x4;
typedef __attribute__((ext_vector_type(8))) __bf16 bf16x8;
typedef __attribute__((ext_vector_type(4))) float  f32x4;

__device__ __forceinline__ unsigned short f2bf(float f) {
  union { float f; unsigned int u; } v; v.f = f;
  unsigned int u = v.u;
  u += 0x7fffu + ((u >> 16) & 1u);   // round-to-nearest-even
  return (unsigned short)(u >> 16);
}

__device__ __forceinline__ float bf2f(unsigned short s) {
  union { unsigned int u; float f; } v; v.u = ((unsigned int)s) << 16;
  return v.f;
}

// Fast softplus: hardware v_exp_f32/v_log_f32 (~10 VALU ops) instead of libm
// expf+log1pf (branchy ~50-70 ops; was VALUBusy 81% / +79us in round 5;
// round 7 confirmed 36% / 98us). Max abs err ~6e-8, below bf16 rounding.
__device__ __forceinline__ float softplus_f(float x) {
  return fmaxf(x, 0.f) + __logf(1.f + __expf(-fabsf(x)));
}

__device__ __forceinline__ short8 pack8(float4 a, float4 b) {
  short8 o;
  o[0] = (short)f2bf(a.x); o[1] = (short)f2bf(a.y);
  o[2] = (short)f2bf(a.z); o[3] = (short)f2bf(a.w);
  o[4] = (short)f2bf(b.x); o[5] = (short)f2bf(b.y);
  o[6] = (short)f2bf(b.z); o[7] = (short)f2bf(b.w);
  return o;
}

// ---- one cast kernel: x -> A2[:,1024:], W1 (interleaved dw/Bw), W2 -------
// W1 row 2h = dw[h,:], row 2h+1 = Bw[h,:]  -> G1 columns become (d,bb) pairs
__global__ __launch_bounds__(256)
void cast_all_kernel(const float* __restrict__ x,
                     const float* __restrict__ dw, const float* __restrict__ Bw,
                     const float* __restrict__ Cw, const float* __restrict__ Dw,
                     unsigned short* __restrict__ A2,
                     unsigned short* __restrict__ W1, unsigned short* __restrict__ W2) {
  const size_t MX = (size_t)MROWS * 1024;       // 16M: x
  const size_t M1 = (size_t)1024 * 1024;        // 1M
  size_t i8 = ((size_t)blockIdx.x * 256 + threadIdx.x) * 8;
  if (i8 < MX) {
    size_t row = i8 >> 10; int col = (int)(i8 & 1023);
    const float4* p = (const float4*)(x + i8);
    *(short8*)(A2 + row * (size_t)KCAT + 1024 + col) = pack8(p[0], p[1]);
  } else if (i8 < MX + 2 * M1) {                // W1 interleaved: row r, h=r>>1
    size_t k = i8 - MX;
    size_t h = k >> 11;                          // channel
    int c = (int)(k & 1023);                     // column
    const float* src = ((k >> 10) & 1) ? (Bw + h * 1024 + c) : (dw + h * 1024 + c);
    const float4* p = (const float4*)src;
    *(short8*)(W1 + k) = pack8(p[0], p[1]);
  } else {                                      // W2 row d: [Cw[d,:] | Dw[d,:]]
    size_t k = i8 - MX - 2 * M1;
    size_t d = k >> 11; int c = (int)(k & 2047);
    const float* src = (c < 1024) ? (Cw + d * 1024 + c) : (Dw + d * 1024 + (c - 1024));
    const float4* p = (const float4*)src;
    *(short8*)(W2 + k) = pack8(p[0], p[1]);
  }
}

// ---- GEMM: C[M,N] = A[M,K] @ B[N,K]^T ------------------------------------
// EXACT round-0/round-7 proven structure (GEMM1 98us, GEMM2 90us). DO NOT
// TOUCH: isolated experiments showed (a) counted-vmcnt rings / 256^2 tiles /
// 1-block-per-CU all regress (r2-r4); (b) fragment-major conflict-free
// staging regresses 1.5x here (r8: FETCH 49->74MB, dur 150us) -- the 8.4M
// bank conflicts are fully hidden under the staging stall in this structure.
// mode 0: f32 out, += bias0[n]+bias1[n]
// mode 2: SSM pointwise epilogue (GEMM1): n even -> d=softplus(acc+db[h]),
//         n odd -> bb = d_neighbor * (acc + Bb[h]); bf16 out. h = n>>1.
__device__ __forceinline__ void stage_tile(const unsigned short* g0, int ld,
                                           unsigned short* s0, int t, int lane) {
#pragma unroll
  for (int half = 0; half < 2; ++half) {
    int c = t + half * 256;
    const unsigned short* g = g0 + (size_t)(c >> 2) * ld + (c & 3) * 8;
    unsigned short* s = s0 + ((size_t)(t - lane) + half * 256) * 8; // wave-uniform base
    __builtin_amdgcn_global_load_lds(
        (const __attribute__((address_space(1))) unsigned int*)g,
        (__attribute__((address_space(3))) unsigned int*)s, 16, 0, 0);
  }
}

__global__ __launch_bounds__(256, 4)
void gemm_bt(const unsigned short* __restrict__ A, int lda,
             const unsigned short* __restrict__ B, int ldb,
             void* __restrict__ Cp, int ldc, int K, int mode,
             const float* __restrict__ bias0, const float* __restrict__ bias1) {
  __shared__ __align__(16) unsigned short As[128 * 32];
  __shared__ __align__(16) unsigned short Bs[128 * 32];
  const int t = threadIdx.x;
  const int lane = t & 63, wave = t >> 6;
  const int quad = lane >> 4, l16 = lane & 15;

  // XCD-aware swizzle: each XCD (bid%8) owns a contiguous M-band, N-fastest,
  // so the weight matrix stays resident in that XCD's 4 MB L2.
  const int Nt = gridDim.x, Mt = gridDim.y;
  int bid = blockIdx.y * Nt + blockIdx.x;
  int xcd = bid & 7;
  int slot = bid >> 3;
  int lm = slot / Nt;
  int ln = slot - lm * Nt;
  const int m0 = (xcd * (Mt >> 3) + lm) * 128;
  const int n0 = ln * 128;

  const int wm = (wave & 1) * 64, wn = (wave >> 1) * 64;

  const unsigned short* Ab = A + (size_t)m0 * lda;
  const unsigned short* Bb = B + (size_t)n0 * ldb;

  f32x4 acc[4][4] = {};

  for (int k0 = 0; k0 < K; k0 += 32) {
    stage_tile(Ab + k0, lda, As, t, lane);
    stage_tile(Bb + k0, ldb, Bs, t, lane);
    __syncthreads();
    short8 af[4], bfr[4];
#pragma unroll
    for (int i = 0; i < 4; ++i)
      af[i] = *(const short8*)(As + ((size_t)(wm + i * 16 + l16)) * 32 + quad * 8);
#pragma unroll
    for (int j = 0; j < 4; ++j)
      bfr[j] = *(const short8*)(Bs + ((size_t)(wn + j * 16 + l16)) * 32 + quad * 8);
#pragma unroll
    for (int i = 0; i < 4; ++i)
#pragma unroll
      for (int j = 0; j < 4; ++j)
        acc[i][j] = __builtin_amdgcn_mfma_f32_16x16x32_bf16(
            __builtin_bit_cast(bf16x8, af[i]),
            __builtin_bit_cast(bf16x8, bfr[j]), acc[i][j], 0, 0, 0);
    __syncthreads();
  }

  if (mode == 0) {
    float* C = (float*)Cp;
#pragma unroll
    for (int i = 0; i < 4; ++i)
#pragma unroll
      for (int j = 0; j < 4; ++j) {
        int n = n0 + wn + j * 16 + l16;
        int mb = m0 + wm + i * 16 + quad * 4;
        float badd = bias0[n] + bias1[n];
#pragma unroll
        for (int r = 0; r < 4; ++r)
          C[(size_t)(mb + r) * ldc + n] = acc[i][j][r] + badd;
      }
  } else {
    // mode 2: fused SSM pointwise. Adjacent lanes hold (dpre, bpre) of the
    // same channel h (W1 rows interleaved); one shfl_xor(1) moves d across.
    unsigned short* C16 = (unsigned short*)Cp;
#pragma unroll
    for (int i = 0; i < 4; ++i)
#pragma unroll
      for (int j = 0; j < 4; ++j) {
        int n = n0 + wn + j * 16 + l16;
        int mb = m0 + wm + i * 16 + quad * 4;
        int h = n >> 1;
        bool isd = (n & 1) == 0;
        float bias = isd ? bias0[h] : bias1[h];   // db[h] : Bb[h]
#pragma unroll
        for (int r = 0; r < 4; ++r) {
          float v = acc[i][j][r] + bias;          // dpre+db  or  bpre+Bb
          float d = softplus_f(v);                // valid on even lanes
          float dn = __shfl_xor(d, 1);            // neighbor's d (for odd lanes)
          float ov = isd ? d : dn * v;            // d  or  bb = d*(bpre+Bb)
          C16[(size_t)(mb + r) * ldc + n] = f2bf(ov);
        }
      }
  }
}

// ---- scan pass A: per-chunk carries (G1 read-only) ----------------------
// G1 row layout: [d0,bb0,d1,bb1,...] interleaved pairs (2048 wide).
// Ring-of-3 prefetch (kept from r8: tail improved ~12us).
__global__ __launch_bounds__(256)
void scan_carry_kernel(const unsigned short* __restrict__ G1,
                       const float* __restrict__ Av, float2* __restrict__ carr) {
  int t = blockIdx.x * 256 + threadIdx.x;      // 131072 = 8 * 64 * 256
  int ho = t & 255, chunk = (t >> 8) & (NCH - 1), b = t >> 14;
  int h0 = ho << 2;
  float4 A0 = *(const float4*)(Av + h0);
  float Ah[4] = {A0.x, A0.y, A0.z, A0.w};
  const unsigned short* base = G1 + ((size_t)(b * LSEQ + chunk * CH)) * KCAT + 2 * h0;
  float hs[4] = {}, sd[4] = {};
  short8 v0 = *(const short8*)(base);
  short8 v1 = *(const short8*)(base + KCAT);
#pragma unroll 4
  for (int l = 0; l < CH; ++l) {
    short8 v2 = v1;
    if (l + 2 < CH)
      v2 = *(const short8*)(base + (size_t)(l + 2) * KCAT);
#pragma unroll
    for (int j = 0; j < 4; ++j) {
      float d  = bf2f((unsigned short)v0[2 * j]);
      float bb = bf2f((unsigned short)v0[2 * j + 1]);
      sd[j] += d;
      hs[j] = fmaf(__expf(d * Ah[j]), hs[j], bb);
    }
    v0 = v1; v1 = v2;
  }
  float2* cb = carr + (size_t)chunk * BH + b * 1024 + h0;
#pragma unroll
  for (int j = 0; j < 4; ++j)
    cb[j] = make_float2(__expf(Ah[j] * sd[j]), hs[j]);
}

// ---- scan pass B: compose carries (lane-contiguous) ---------------------
// Only 32 blocks on 256 CUs -> latency-bound with 1 outstanding load
// (~0.17 TB/s aggregate). Ring-of-8 prefetch, fully unrolled so buf[c&7]
// is always a compile-time index (rule: runtime-indexed arrays -> scratch).
__global__ __launch_bounds__(256)
void scan_comb_kernel(const float2* __restrict__ carr, float* __restrict__ Hc) {
  int t = blockIdx.x * 256 + threadIdx.x;   // 8192 = B*DH
  float2 buf[8];
#pragma unroll
  for (int i = 0; i < 8; ++i) buf[i] = carr[(size_t)i * BH + t];
  float H = 0.f;
#pragma unroll
  for (int c = 0; c < NCH; ++c) {
    float2 ah = buf[c & 7];
    if (c + 8 < NCH) buf[c & 7] = carr[(size_t)(c + 8) * BH + t];
    Hc[(size_t)c * BH + t] = H;              // carry-in for chunk c
    H = fmaf(ah.x, H, ah.y);
  }
}

// ---- scan pass C: recompute with carry, emit h bf16 into A2[:,0:1024] ---
__global__ __launch_bounds__(256)
void scan_final_kernel(const unsigned short* __restrict__ G1,
                       const float* __restrict__ Av, const float* __restrict__ Hc,
                       unsigned short* __restrict__ A2) {
  int t = blockIdx.x * 256 + threadIdx.x;      // 131072
  int ho = t & 255, chunk = (t >> 8) & (NCH - 1), b = t >> 14;
  int h0 = ho << 2;
  float4 A0 = *(const float4*)(Av + h0);
  float Ah[4] = {A0.x, A0.y, A0.z, A0.w};
  const unsigned short* base = G1 + ((size_t)(b * LSEQ + chunk * CH)) * KCAT + 2 * h0;
  unsigned short* obase = A2 + ((size_t)(b * LSEQ + chunk * CH)) * KCAT + h0;
  const float* hb = Hc + (size_t)chunk * BH + b * 1024 + h0;
  float hs[4];
#pragma unroll
  for (int j = 0; j < 4; ++j) hs[j] = hb[j];
  short8 v0 = *(const short8*)(base);
  short8 v1 = *(const short8*)(base + KCAT);
#pragma unroll 4
  for (int l = 0; l < CH; ++l) {
    short8 v2 = v1;
    if (l + 2 < CH)
      v2 = *(const short8*)(base + (size_t)(l + 2) * KCAT);
    s16x4 o;
#pragma unroll
    for (int j = 0; j < 4; ++j) {
      float d  = bf2f((unsigned short)v0[2 * j]);
      float bb = bf2f((unsigned short)v0[2 * j + 1]);
      hs[j] = fmaf(__expf(d * Ah[j]), hs[j], bb);
      o[j] = (short)f2bf(hs[j]);
    }
    *(s16x4*)(obase + (size_t)l * KCAT) = o;
    v0 = v1; v1 = v2;
  }
}

extern "C" void kernel_launch(void* const* d_in, const int* in_sizes, int n_in,
                              void* d_out, int out_size, void* d_ws, size_t ws_size,
                              hipStream_t stream) {
  const float* x  = (const float*)d_in[0];
  const float* Av = (const float*)d_in[1];
  const float* Bw = (const float*)d_in[2];
  const float* Bb = (const float*)d_in[3];
  const float* Cw = (const float*)d_in[4];
  const float* Cb = (const float*)d_in[5];
  const float* Dw = (const float*)d_in[6];
  const float* Db = (const float*)d_in[7];
  const float* dw = (const float*)d_in[8];
  const float* db = (const float*)d_in[9];
  float* out = (float*)d_out;

  // Workspace (138 MiB):
  //   A2 [16384,2048] bf16 = 64 MiB ([h | x])
  //   G1 [16384,2048] bf16 = 64 MiB ((d,bb) interleaved pairs)
  //   W1 [2048,1024]  bf16 =  4 MiB (interleaved dw/Bw; reused as carr)
  //   W2 [1024,2048]  bf16 =  4 MiB ([Cw|Dw])
  //   Hc [64,8192]    f32  =  2 MiB
  const size_t sz_big = (size_t)MROWS * KCAT * 2;
  const size_t sz_w   = (size_t)2048 * 1024 * 2;
  const size_t sz_hc  = (size_t)NCH * BH * 4;
  const size_t need = 2 * sz_big + 2 * sz_w + sz_hc;
  if (ws_size < need) return;

  char* w = (char*)d_ws;
  unsigned short* A2 = (unsigned short*)w; w += sz_big;
  unsigned short* G1 = (unsigned short*)w; w += sz_big;
  unsigned short* W1 = (unsigned short*)w; w += sz_w;
  unsigned short* W2 = (unsigned short*)w; w += sz_w;
  float* Hc = (float*)w;                   w += sz_hc;
  float2* carr = (float2*)W1;  // W1 dead after GEMM1; carr = NCH*BH*8 = 4 MiB exactly

  // cast everything (x, W1, W2) in one launch
  const size_t cast_elems = (size_t)MROWS * 1024 + 2 * (size_t)2048 * 1024;
  cast_all_kernel<<<(int)(cast_elems / (256 * 8)), 256, 0, stream>>>(
      x, dw, Bw, Cw, Dw, A2, W1, W2);

  // GEMM1 + fused pointwise: G1 = pointwise(x @ W1^T)  (M=16384,N=2048,K=1024)
  dim3 g1(KCAT / 128, MROWS / 128);        // (16, 128)
  gemm_bt<<<g1, 256, 0, stream>>>(A2 + 1024, KCAT, W1, 1024, G1, KCAT, 1024, 2,
                                  db, Bb);

  // chunked scan: carries (read-only over G1), compose, final
  scan_carry_kernel<<<(NBATCH * NCH * (DHID / CPT)) / 256, 256, 0, stream>>>(
      G1, Av, carr);
  scan_comb_kernel<<<BH / 256, 256, 0, stream>>>(carr, Hc);
  scan_final_kernel<<<(NBATCH * NCH * (DHID / CPT)) / 256, 256, 0, stream>>>(
      G1, Av, Hc, A2);

  // GEMM2: out = [h | x] @ [Cw|Dw]^T + Cb + Db  (M=16384,N=1024,K=2048), f32
  dim3 g2(DMODEL / 128, MROWS / 128);      // (8, 128)
  gemm_bt<<<g2, 256, 0, stream>>>(A2, KCAT, W2, KCAT, out, DMODEL, KCAT, 0, Cb, Db);
}